// Round 17
// baseline (755.068 us; speedup 1.0000x reference)
//
#include <hip/hip_runtime.h>

// LSTM B=512,T=512,D=128,H=64,O=1. Gate order i,f,g,o.
// K1: pre = x@Wih0^T + bih0+bhh0 — fp16 MFMA (R15-proven, ~70us).
// K2: fused 2-layer recurrence, weights in VGPRs via VOLATILE-ASM loads.
//   R3-R11: compiler demotes loop-invariant weight LOADS (legal re-execution)
//   under every source-level knob. R12-R16: LDS-streamed fp16 weights plateau
//   at ~2700 cyc/step (96 w-b128 issues/block/step irreducible). New weapon:
//   weights DEFINED by asm volatile global_load_dwordx4 — volatile asm cannot
//   be duplicated/sunk, so re-execution inside the loop is ILLEGAL, and
//   waves_per_eu(3,3) gives an honest 170-VGPR budget (R10-proven clamp) so
//   spilling has no incentive (~140 live). Dataflow = R10's (absmax 0.0):
//   768 thr = 3 matrix groups (m: Whh0/Wih1/Whh1), thread owns 4 gate-rows of
//   unit j, k-slice [16qt,16qt+16), quad DPP butterfly (xor1+xor2) -> full
//   64-k sums in-lane; m2 publishes Whh1.h1 via zp2; skewed layers; C=2
//   batches/block (256 blocks, 1 pass); 2 barriers/step. fp32 throughout.
// ws: 512*512*256*4 = 256 MiB fp32 pre (written by K1, read-only in K2).

#define TSTEPS 512

typedef float f32x4 __attribute__((ext_vector_type(4)));
typedef _Float16 half8 __attribute__((ext_vector_type(8)));
typedef __attribute__((ext_vector_type(4))) float facc;

__device__ __forceinline__ float sigf(float x){ return 1.0f/(1.0f+__expf(-x)); }
__device__ __forceinline__ float tanh_fast(float x){
  float ax=fabsf(x); float e=__expf(-2.0f*ax); float r=(1.0f-e)/(1.0f+e); return copysignf(r,x);
}
// a + dpp_quad_perm(b); 0xB1 = xor1 [1,0,3,2], 0x4E = xor2 [2,3,0,1]
template<int CTRL>
__device__ __forceinline__ float add_dpp(float a, float b){
  return a + __int_as_float(__builtin_amdgcn_update_dpp(
      0, __float_as_int(b), CTRL, 0xF, 0xF, true));
}
__device__ __forceinline__ float dot4v(f32x4 w, f32x4 h, float acc){
  acc = fmaf(w[0], h[0], acc); acc = fmaf(w[1], h[1], acc);
  acc = fmaf(w[2], h[2], acc); acc = fmaf(w[3], h[3], acc);
  return acc;
}

// ---------------- K1: input projection GEMM (fp16 MFMA, R15) ----------------
__global__ __launch_bounds__(256) void k_inproj(
    const float* __restrict__ x, const float* __restrict__ W,
    const float* __restrict__ bih, const float* __restrict__ bhh,
    float* __restrict__ pre)
{
    __shared__ __align__(16) _Float16 Ah[64][136];
    __shared__ __align__(16) _Float16 Bh[256][136];
    const int tid = threadIdx.x;
    const long row0 = (long)blockIdx.x * 64;

    {
        const int r = tid >> 2, c0 = (tid & 3) * 32;
        const float4* src = (const float4*)(x + (row0 + r) * 128 + c0);
#pragma unroll
        for (int i = 0; i < 4; ++i) {
            float4 v0 = src[2 * i], v1 = src[2 * i + 1];
            half8 hv = { (_Float16)v0.x, (_Float16)v0.y, (_Float16)v0.z, (_Float16)v0.w,
                         (_Float16)v1.x, (_Float16)v1.y, (_Float16)v1.z, (_Float16)v1.w };
            *(half8*)&Ah[r][c0 + 8 * i] = hv;
        }
    }
    {
        const float4* src = (const float4*)(W + tid * 128);
#pragma unroll
        for (int i = 0; i < 16; ++i) {
            float4 v0 = src[2 * i], v1 = src[2 * i + 1];
            half8 hv = { (_Float16)v0.x, (_Float16)v0.y, (_Float16)v0.z, (_Float16)v0.w,
                         (_Float16)v1.x, (_Float16)v1.y, (_Float16)v1.z, (_Float16)v1.w };
            *(half8*)&Bh[tid][8 * i] = hv;
        }
    }
    __syncthreads();

    const int w  = tid >> 6;
    const int l  = tid & 63;
    const int lm = l & 15;
    const int lk = l >> 4;
    const int n0 = w * 64;

    facc acc[4][4];
#pragma unroll
    for (int mi = 0; mi < 4; ++mi)
#pragma unroll
        for (int ni = 0; ni < 4; ++ni) acc[mi][ni] = (facc){0.f, 0.f, 0.f, 0.f};

#pragma unroll
    for (int ks = 0; ks < 4; ++ks) {
        const int kk = ks * 32 + lk * 8;
        half8 Af[4], Bf[4];
#pragma unroll
        for (int mi = 0; mi < 4; ++mi) Af[mi] = *(const half8*)&Ah[mi * 16 + lm][kk];
#pragma unroll
        for (int ni = 0; ni < 4; ++ni) Bf[ni] = *(const half8*)&Bh[n0 + ni * 16 + lm][kk];
#pragma unroll
        for (int mi = 0; mi < 4; ++mi)
#pragma unroll
            for (int ni = 0; ni < 4; ++ni)
                acc[mi][ni] = __builtin_amdgcn_mfma_f32_16x16x32_f16(
                    Af[mi], Bf[ni], acc[mi][ni], 0, 0, 0);
    }

    float bs[4];
#pragma unroll
    for (int ni = 0; ni < 4; ++ni) {
        const int n = n0 + ni * 16 + lm;
        bs[ni] = bih[n] + bhh[n];
    }
#pragma unroll
    for (int mi = 0; mi < 4; ++mi) {
#pragma unroll
        for (int ni = 0; ni < 4; ++ni) {
            const int n = n0 + ni * 16 + lm;
#pragma unroll
            for (int r = 0; r < 4; ++r) {
                const long row = row0 + mi * 16 + lk * 4 + r;
                pre[row * 256 + n] = acc[mi][ni][r] + bs[ni];
            }
        }
    }
}

// ---------------- K2: fused 2-layer recurrence + head ----------------
// 256 blocks x 768 thr (12 waves). m=tid>>8: 0=Whh0, 1=Wih1, 2=Whh1.
__global__
__attribute__((amdgpu_flat_work_group_size(768, 768)))
__attribute__((amdgpu_waves_per_eu(3, 3)))
void k_fused(
    const float* __restrict__ Whh0, const float* __restrict__ Wih1,
    const float* __restrict__ Whh1,
    const float* __restrict__ bih1, const float* __restrict__ bhh1,
    const float* __restrict__ Wfc,  const float* __restrict__ bfc,
    const float* __restrict__ pre,  float* __restrict__ out)
{
    const int tid = threadIdx.x;
    const int m   = tid >> 8;        // matrix group
    const int s   = tid & 255;
    const int j   = s >> 2;          // hidden unit 0..63
    const int qt  = s & 3;           // k-quarter
    const long bb = (long)blockIdx.x * 2;

    __shared__ __align__(16) float h0s[2][2][64];   // [parity][batch][unit]
    __shared__ __align__(16) float h1s[2][2][64];
    __shared__ float zp2[2][4][64];                 // [batch][gate][unit]
    __shared__ float hfin[2][64];

    // ---- weights: 64 floats/thread in VGPRs, DEFINED BY VOLATILE ASM ----
    // volatile asm cannot be duplicated or sunk into the loop => the load
    // cannot be re-executed per-step (the R3-R11 demotion is illegal here).
    const float* Wm = (m == 0) ? Whh0 : (m == 1) ? Wih1 : Whh1;
    f32x4 w4[16];
#pragma unroll
    for (int g = 0; g < 4; ++g) {
        const float* base = Wm + (g * 64 + j) * 64 + qt * 16;
#pragma unroll
        for (int i = 0; i < 4; ++i)
            asm volatile("global_load_dwordx4 %0, %1, off"
                         : "=v"(w4[4 * g + i]) : "v"(base + 4 * i));
    }
    asm volatile("s_waitcnt vmcnt(0)" ::: "memory");

    // zero h state, BOTH parities (parity-1 h1 is read at n=1 before written)
    if (tid < 256) {
        ((float*)h0s)[tid] = 0.0f;
        ((float*)h1s)[tid] = 0.0f;
    }

    // updater-lane constants (qt even: batch c = qt>>1)
    const int c  = qt >> 1;
    float bias1v[4] = {0, 0, 0, 0};
    float pc[4] = {0, 0, 0, 0};
    const float* pbase = pre + (bb + c) * (long)(TSTEPS * 256);
    if (!(qt & 1)) {
        if (m == 0) {
#pragma unroll
            for (int g = 0; g < 4; ++g) pc[g] = pbase[g * 64 + j];   // t=0
        } else if (m == 1) {
#pragma unroll
            for (int g = 0; g < 4; ++g) bias1v[g] = bih1[g * 64 + j] + bhh1[g * 64 + j];
        }
    }

    float cst = 0.0f, h1keep = 0.0f;
    int p = 0;
    __syncthreads();

#pragma unroll 1
    for (int n = 0; n <= TSTEPS; ++n) {
        // h slices for my matrix (old state): m<2 -> h0, m==2 -> h1; both batches
        const float (*hs)[64] = (m == 2) ? h1s[p] : h0s[p];
        f32x4 hA[4], hB[4];
        {
            const f32x4* a = (const f32x4*)&hs[0][qt * 16];
            const f32x4* b = (const f32x4*)&hs[1][qt * 16];
#pragma unroll
            for (int i = 0; i < 4; ++i) { hA[i] = a[i]; hB[i] = b[i]; }
        }

        // prefetch next pre (m0 updater lanes only)
        float pn_[4] = {0, 0, 0, 0};
        if (m == 0 && !(qt & 1)) {
            const int tn = (n < TSTEPS - 1) ? n + 1 : 0;
#pragma unroll
            for (int g = 0; g < 4; ++g) pn_[g] = pbase[tn * 256 + g * 64 + j];
        }

        // ---- dots: 4 gates x 2 batches, k-slice 16 each ----
        float zA[4], zB[4];
#pragma unroll
        for (int g = 0; g < 4; ++g) {
            float a0 = dot4v(w4[4 * g + 0], hA[0], 0.0f);
            float a1 = dot4v(w4[4 * g + 1], hA[1], 0.0f);
            a0 = dot4v(w4[4 * g + 2], hA[2], a0);
            a1 = dot4v(w4[4 * g + 3], hA[3], a1);
            float ta = a0 + a1;
            float b0 = dot4v(w4[4 * g + 0], hB[0], 0.0f);
            float b1 = dot4v(w4[4 * g + 1], hB[1], 0.0f);
            b0 = dot4v(w4[4 * g + 2], hB[2], b0);
            b1 = dot4v(w4[4 * g + 3], hB[3], b1);
            float tb = b0 + b1;
            // quad butterfly -> full 64-k sums in every lane
            ta = add_dpp<0xB1>(ta, ta); ta = add_dpp<0x4E>(ta, ta);
            tb = add_dpp<0xB1>(tb, tb); tb = add_dpp<0x4E>(tb, tb);
            zA[g] = ta; zB[g] = tb;
        }

        // m2 publishes Whh1 . h1 partials (its batch's copy)
        if (m == 2 && !(qt & 1)) {
#pragma unroll
            for (int g = 0; g < 4; ++g) zp2[c][g][j] = c ? zB[g] : zA[g];
        }
        __syncthreads();   // zp2 visible

        // ---- cell updates (qt-even lanes; batch c) ----
        if (!(qt & 1)) {
            const float* zz = c ? zB : zA;
            if (m == 0) {
                if (n < TSTEPS) {
                    float i_ = sigf(pc[0] + zz[0]);
                    float f_ = sigf(pc[1] + zz[1]);
                    float g_ = tanh_fast(pc[2] + zz[2]);
                    float o_ = sigf(pc[3] + zz[3]);
                    cst = fmaf(f_, cst, i_ * g_);
                    h0s[p ^ 1][c][j] = o_ * tanh_fast(cst);
                }
#pragma unroll
                for (int g = 0; g < 4; ++g) pc[g] = pn_[g];
            } else if (m == 1) {
                if (n >= 1) {
                    float i_ = sigf(bias1v[0] + zz[0] + zp2[c][0][j]);
                    float f_ = sigf(bias1v[1] + zz[1] + zp2[c][1][j]);
                    float g_ = tanh_fast(bias1v[2] + zz[2] + zp2[c][2][j]);
                    float o_ = sigf(bias1v[3] + zz[3] + zp2[c][3][j]);
                    cst = fmaf(f_, cst, i_ * g_);
                    float h = o_ * tanh_fast(cst);
                    h1keep = h;
                    h1s[p ^ 1][c][j] = h;
                }
            }
        }
        __syncthreads();   // new h visible
        p ^= 1;
    }

    // ---- head: out[bb+c] = h1(T-1) . Wfc + bfc ----
    if (m == 1 && !(qt & 1)) hfin[c][j] = h1keep;
    __syncthreads();
    if (tid < 128) {
        const int cc = tid >> 6, jj = tid & 63;
        float v = hfin[cc][jj] * Wfc[jj];
#pragma unroll
        for (int off = 32; off > 0; off >>= 1) v += __shfl_down(v, off);
        if (jj == 0) out[bb + cc] = v + bfc[0];
    }
}

extern "C" void kernel_launch(void* const* d_in, const int* in_sizes, int n_in,
                              void* d_out, int out_size, void* d_ws, size_t ws_size,
                              hipStream_t stream)
{
    const float* x    = (const float*)d_in[0];
    const float* Wih0 = (const float*)d_in[1];
    const float* Whh0 = (const float*)d_in[2];
    const float* bih0 = (const float*)d_in[3];
    const float* bhh0 = (const float*)d_in[4];
    const float* Wih1 = (const float*)d_in[5];
    const float* Whh1 = (const float*)d_in[6];
    const float* bih1 = (const float*)d_in[7];
    const float* bhh1 = (const float*)d_in[8];
    const float* Wfc  = (const float*)d_in[9];
    const float* bfc  = (const float*)d_in[10];
    float* out = (float*)d_out;
    float* pre = (float*)d_ws;  // [B][T][256] fp32 = 256 MiB

    k_inproj<<<4096, 256, 0, stream>>>(x, Wih0, bih0, bhh0, pre);
    k_fused<<<256, 768, 0, stream>>>(Whh0, Wih1, Whh1, bih1, bhh1, Wfc, bfc, pre, out);
}

// Round 18
// 653.072 us; speedup vs baseline: 1.1562x; 1.1562x over previous
//
#include <hip/hip_runtime.h>

// LSTM B=512,T=512,D=128,H=64,O=1. Gate order i,f,g,o.
// K1: pre = x@Wih0^T + bih0+bhh0 — fp16 MFMA (R15-proven, ~70us).
// K2: R13 structure with weights moved LDS -> AGPR FILE.
//   R3-R11,R17: VGPR-resident weights impossible (8 mechanisms tried; the
//   backend sinks/spills loop-invariant loads regardless of pins/volatile/
//   waves_per_eu). R12-R16: LDS-streaming plateaus at ~2570 cyc/step, with
//   96 w-b128 issues/block/step = 1150 cyc the dominant term. K2 uses no
//   MFMA, so AGPRs are idle: park the 32 packed-fp16 weight dwords/thread
//   there via explicit v_accvgpr_write/read ("a" constraint). Not loads =>
//   not sinkable; ~32 AGPR + ~60 VGPR << 170 budget => no spill pressure;
//   volatile reads => can't be hoisted into VGPR residency. R6 precedent:
//   compiler itself used AGPRs for weights when capped.
//   Everything else = R13 verbatim (absmax 4.9e-4): 768 thr, C=2 batches,
//   quad k-split, select-free DPP merges, skewed layers, 2 barriers/step.
// ws: 512*512*256*4 = 256 MiB fp32 pre (written by K1, read-only in K2).

#define TSTEPS 512

typedef _Float16 h2v __attribute__((ext_vector_type(2)));
typedef _Float16 half8 __attribute__((ext_vector_type(8)));
typedef __attribute__((ext_vector_type(4))) float facc;
union HU { unsigned u; h2v h; };

__device__ __forceinline__ float sigf(float x){ return 1.0f/(1.0f+__expf(-x)); }
__device__ __forceinline__ float tanh_fast(float x){
  float ax=fabsf(x); float e=__expf(-2.0f*ax); float r=(1.0f-e)/(1.0f+e); return copysignf(r,x);
}
__device__ __forceinline__ unsigned packh(float a, float b){
  unsigned short la = __builtin_bit_cast(unsigned short, (_Float16)a);
  unsigned short lb = __builtin_bit_cast(unsigned short, (_Float16)b);
  return (unsigned)la | ((unsigned)lb << 16);
}
__device__ __forceinline__ float dot2f(unsigned wu, unsigned hu, float acc){
#if __has_builtin(__builtin_amdgcn_fdot2)
  HU w; w.u = wu; HU x; x.u = hu;
  return __builtin_amdgcn_fdot2(w.h, x.h, acc, false);
#else
  HU w; w.u = wu; HU x; x.u = hu;
  acc = fmaf((float)w.h[0], (float)x.h[0], acc);
  acc = fmaf((float)w.h[1], (float)x.h[1], acc);
  return acc;
#endif
}
template<int CTRL>
__device__ __forceinline__ float add_dpp(float a, float b){
  return a + __int_as_float(__builtin_amdgcn_update_dpp(
      0, __float_as_int(b), CTRL, 0xF, 0xF, true));
}
__device__ __forceinline__ float dot16(uint4 w0, uint4 w1, uint4 h0, uint4 h1){
  float a = 0.0f;
  a = dot2f(w0.x, h0.x, a); a = dot2f(w0.y, h0.y, a);
  a = dot2f(w0.z, h0.z, a); a = dot2f(w0.w, h0.w, a);
  a = dot2f(w1.x, h1.x, a); a = dot2f(w1.y, h1.y, a);
  a = dot2f(w1.z, h1.z, a); a = dot2f(w1.w, h1.w, a);
  return a;
}
// AGPR park/fetch: "a" = AGPR register class. Write once (volatile: cannot be
// deleted/duplicated); read volatile (cannot be hoisted out of the loop into
// VGPR residency, which would recreate the demotion pressure).
__device__ __forceinline__ void awrite(unsigned &dst, unsigned v){
  asm volatile("v_accvgpr_write_b32 %0, %1" : "=a"(dst) : "v"(v));
}
__device__ __forceinline__ unsigned aread(unsigned &src){
  unsigned r;
  asm volatile("v_accvgpr_read_b32 %0, %1" : "=v"(r) : "a"(src));
  return r;
}

// ---------------- K1: input projection GEMM (fp16 MFMA, R15) ----------------
__global__ __launch_bounds__(256) void k_inproj(
    const float* __restrict__ x, const float* __restrict__ W,
    const float* __restrict__ bih, const float* __restrict__ bhh,
    float* __restrict__ pre)
{
    __shared__ __align__(16) _Float16 Ah[64][136];
    __shared__ __align__(16) _Float16 Bh[256][136];
    const int tid = threadIdx.x;
    const long row0 = (long)blockIdx.x * 64;

    {
        const int r = tid >> 2, c0 = (tid & 3) * 32;
        const float4* src = (const float4*)(x + (row0 + r) * 128 + c0);
#pragma unroll
        for (int i = 0; i < 4; ++i) {
            float4 v0 = src[2 * i], v1 = src[2 * i + 1];
            half8 hv = { (_Float16)v0.x, (_Float16)v0.y, (_Float16)v0.z, (_Float16)v0.w,
                         (_Float16)v1.x, (_Float16)v1.y, (_Float16)v1.z, (_Float16)v1.w };
            *(half8*)&Ah[r][c0 + 8 * i] = hv;
        }
    }
    {
        const float4* src = (const float4*)(W + tid * 128);
#pragma unroll
        for (int i = 0; i < 16; ++i) {
            float4 v0 = src[2 * i], v1 = src[2 * i + 1];
            half8 hv = { (_Float16)v0.x, (_Float16)v0.y, (_Float16)v0.z, (_Float16)v0.w,
                         (_Float16)v1.x, (_Float16)v1.y, (_Float16)v1.z, (_Float16)v1.w };
            *(half8*)&Bh[tid][8 * i] = hv;
        }
    }
    __syncthreads();

    const int w  = tid >> 6;
    const int l  = tid & 63;
    const int lm = l & 15;
    const int lk = l >> 4;
    const int n0 = w * 64;

    facc acc[4][4];
#pragma unroll
    for (int mi = 0; mi < 4; ++mi)
#pragma unroll
        for (int ni = 0; ni < 4; ++ni) acc[mi][ni] = (facc){0.f, 0.f, 0.f, 0.f};

#pragma unroll
    for (int ks = 0; ks < 4; ++ks) {
        const int kk = ks * 32 + lk * 8;
        half8 Af[4], Bf[4];
#pragma unroll
        for (int mi = 0; mi < 4; ++mi) Af[mi] = *(const half8*)&Ah[mi * 16 + lm][kk];
#pragma unroll
        for (int ni = 0; ni < 4; ++ni) Bf[ni] = *(const half8*)&Bh[n0 + ni * 16 + lm][kk];
#pragma unroll
        for (int mi = 0; mi < 4; ++mi)
#pragma unroll
            for (int ni = 0; ni < 4; ++ni)
                acc[mi][ni] = __builtin_amdgcn_mfma_f32_16x16x32_f16(
                    Af[mi], Bf[ni], acc[mi][ni], 0, 0, 0);
    }

    float bs[4];
#pragma unroll
    for (int ni = 0; ni < 4; ++ni) {
        const int n = n0 + ni * 16 + lm;
        bs[ni] = bih[n] + bhh[n];
    }
#pragma unroll
    for (int mi = 0; mi < 4; ++mi) {
#pragma unroll
        for (int ni = 0; ni < 4; ++ni) {
            const int n = n0 + ni * 16 + lm;
#pragma unroll
            for (int r = 0; r < 4; ++r) {
                const long row = row0 + mi * 16 + lk * 4 + r;
                pre[row * 256 + n] = acc[mi][ni][r] + bs[ni];
            }
        }
    }
}

// ---------------- K2: fused 2-layer recurrence + head (R13 + AGPR weights) --
__global__
__attribute__((amdgpu_flat_work_group_size(768, 768)))
__attribute__((amdgpu_waves_per_eu(3)))
void k_fused(
    const float* __restrict__ Whh0, const float* __restrict__ Wih1,
    const float* __restrict__ Whh1,
    const float* __restrict__ bih1, const float* __restrict__ bhh1,
    const float* __restrict__ Wfc,  const float* __restrict__ bfc,
    const float* __restrict__ pre,  float* __restrict__ out)
{
    const int tid = threadIdx.x;
    const int ll  = tid & 3;          // lane-in-quad = k-slice index
    const int q   = tid >> 2;         // quad 0..191: rows 4q..4q+3 (global 0..767)
    const int m   = q >> 6;           // matrix: 0=Whh0, 1=Wih1, 2=Whh1
    const int lay = (m == 2) ? 1 : 0; // h layer my matrix consumes
    const int cA  = (ll >> 1) & 1;    // surviving batch slot
    const int cB  = cA ^ 1;

    __shared__ unsigned hp[2][2][2][32];    // 1KB [par][batch][layer] 64 fp16
    __shared__ float zl[2][768];            // 6KB dot results [batch][row]

    // ---- one-time: pack my 4 rows (permuted) x k-slice -> 32 dwords in AGPRs
    unsigned wa[32];
    {
        const float* Wm = (m == 0) ? Whh0 : ((m == 1) ? Wih1 : Whh1);
        const int rofs[4] = { (ll & 1), 2 + (ll & 1), 1 - (ll & 1), 3 - (ll & 1) };
#pragma unroll
        for (int rs = 0; rs < 4; ++rs) {
            const int rr = (4 * q + rofs[rs]) & 255;       // row within matrix
            const float4* src = (const float4*)(Wm + rr * 64 + 16 * ll);
            float4 f0 = src[0], f1 = src[1], f2 = src[2], f3 = src[3];
            awrite(wa[8 * rs + 0], packh(f0.x, f0.y));
            awrite(wa[8 * rs + 1], packh(f0.z, f0.w));
            awrite(wa[8 * rs + 2], packh(f1.x, f1.y));
            awrite(wa[8 * rs + 3], packh(f1.z, f1.w));
            awrite(wa[8 * rs + 4], packh(f2.x, f2.y));
            awrite(wa[8 * rs + 5], packh(f2.z, f2.w));
            awrite(wa[8 * rs + 6], packh(f3.x, f3.y));
            awrite(wa[8 * rs + 7], packh(f3.z, f3.w));
        }
    }
    if (tid < 256) ((unsigned*)hp)[tid] = 0;   // h_{-1}=0 both parities

    // ---- updater role (tid<256): c=batch, l=layer, j=unit ----
    const int c_u = tid >> 7;
    const int l_u = (tid >> 6) & 1;
    const int j_u = tid & 63;
    const long bb = (long)blockIdx.x * 2;
    float bias1v[4] = {0, 0, 0, 0};
    float pc[4] = {0, 0, 0, 0};
    if (tid < 256) {
        if (l_u == 1) {
#pragma unroll
            for (int g = 0; g < 4; ++g) bias1v[g] = bih1[g * 64 + j_u] + bhh1[g * 64 + j_u];
        } else {
            const float* pb = pre + (bb + c_u) * TSTEPS * 256;
#pragma unroll
            for (int g = 0; g < 4; ++g) pc[g] = pb[g * 64 + j_u];   // t=0
        }
    }
    float cst = 0.0f, h1last = 0.0f;
    int p = 0;
    __syncthreads();

#pragma unroll 1
    for (int n = 0; n <= TSTEPS; ++n) {
        // prefetch pre for t=n+1 (layer-0 updaters)
        float pn[4] = {0, 0, 0, 0};
        if (tid < 256 && l_u == 0) {
            const int tn = (n + 1 < TSTEPS) ? n + 1 : 0;
            const float* pb = pre + ((bb + c_u) * TSTEPS + tn) * 256;
#pragma unroll
            for (int g = 0; g < 4; ++g) pn[g] = pb[g * 64 + j_u];
        }

        // ---- h slices (my k-slice, both batch slots): 4 b128, broadcast ----
        uint4 hA0 = *(const uint4*)&hp[p][cA][lay][ll * 8];
        uint4 hA1 = *(const uint4*)&hp[p][cA][lay][ll * 8 + 4];
        uint4 hB0 = *(const uint4*)&hp[p][cB][lay][ll * 8];
        uint4 hB1 = *(const uint4*)&hp[p][cB][lay][ll * 8 + 4];

        // ---- partial dots: weights fetched from AGPRs (no DS traffic) ----
        float pA[4], pB[4];
#pragma unroll
        for (int rs = 0; rs < 4; ++rs) {
            uint4 w0, w1;
            w0.x = aread(wa[8 * rs + 0]); w0.y = aread(wa[8 * rs + 1]);
            w0.z = aread(wa[8 * rs + 2]); w0.w = aread(wa[8 * rs + 3]);
            w1.x = aread(wa[8 * rs + 4]); w1.y = aread(wa[8 * rs + 5]);
            w1.z = aread(wa[8 * rs + 6]); w1.w = aread(wa[8 * rs + 7]);
            pA[rs] = dot16(w0, w1, hA0, hA1);
            pB[rs] = dot16(w0, w1, hB0, hB1);
        }

        // ---- select-free merges ----
        float q0A = add_dpp<0xB1>(pA[0], pA[2]);
        float q1A = add_dpp<0xB1>(pA[1], pA[3]);
        float q0B = add_dpp<0xB1>(pB[0], pB[2]);
        float q1B = add_dpp<0xB1>(pB[1], pB[3]);
        float r0 = add_dpp<0x4E>(q0A, q0B);
        float r1 = add_dpp<0x4E>(q1A, q1B);

        const int R0 = 4 * q + (ll & 1);
        zl[cA][R0]     = r0;
        zl[cA][R0 + 2] = r1;
        __syncthreads();   // zl ready

        // ---- cell updates ----
        if (tid < 256) {
            const bool valid = (l_u == 0) ? (n < TSTEPS) : (n >= 1);
            if (valid) {
                float z[4];
                if (l_u == 0) {
#pragma unroll
                    for (int g = 0; g < 4; ++g) z[g] = pc[g] + zl[c_u][g * 64 + j_u];
                } else {
#pragma unroll
                    for (int g = 0; g < 4; ++g)
                        z[g] = bias1v[g] + zl[c_u][256 + g * 64 + j_u] + zl[c_u][512 + g * 64 + j_u];
                }
                float i_ = sigf(z[0]), f_ = sigf(z[1]), g_ = tanh_fast(z[2]), o_ = sigf(z[3]);
                cst = fmaf(f_, cst, i_ * g_);
                float h = o_ * tanh_fast(cst);
                if (l_u) h1last = h;
                ((unsigned short*)&hp[p ^ 1][c_u][l_u][0])[j_u] =
                    __builtin_bit_cast(unsigned short, (_Float16)h);
            }
        }
        __syncthreads();   // new h visible
        p ^= 1;
        if (tid < 256 && l_u == 0) {
            pc[0] = pn[0]; pc[1] = pn[1]; pc[2] = pn[2]; pc[3] = pn[3];
        }
    }

    // ---- head: out[bb+c] = h1_{T-1} . Wfc + bfc ----
    if (tid < 256 && l_u == 1) {
        float v = h1last * Wfc[j_u];
#pragma unroll
        for (int off = 32; off > 0; off >>= 1) v += __shfl_down(v, off);
        if (j_u == 0) out[bb + c_u] = v + bfc[0];
    }
}

extern "C" void kernel_launch(void* const* d_in, const int* in_sizes, int n_in,
                              void* d_out, int out_size, void* d_ws, size_t ws_size,
                              hipStream_t stream)
{
    const float* x    = (const float*)d_in[0];
    const float* Wih0 = (const float*)d_in[1];
    const float* Whh0 = (const float*)d_in[2];
    const float* bih0 = (const float*)d_in[3];
    const float* bhh0 = (const float*)d_in[4];
    const float* Wih1 = (const float*)d_in[5];
    const float* Whh1 = (const float*)d_in[6];
    const float* bih1 = (const float*)d_in[7];
    const float* bhh1 = (const float*)d_in[8];
    const float* Wfc  = (const float*)d_in[9];
    const float* bfc  = (const float*)d_in[10];
    float* out = (float*)d_out;
    float* pre = (float*)d_ws;  // [B][T][256] fp32 = 256 MiB

    k_inproj<<<4096, 256, 0, stream>>>(x, Wih0, bih0, bhh0, pre);
    k_fused<<<256, 768, 0, stream>>>(Whh0, Wih1, Whh1, bih1, bhh1, Wfc, bfc, pre, out);
}